// Round 21
// baseline (107.839 us; speedup 1.0000x reference)
//
#include <hip/hip_runtime.h>

// MemoryProjection: x_t = A x_{t-1} + in_t * Bd, out = all states (2048,8,64,64) fp32.
// Chunked: out[j*64+tau] = A^(tau+1) x0_j + sum_{k<=tau} (A^(tau-k) Bd) in[j*64+k]
// => one fp16 MFMA GEMM: C[m=(j,q)][nn=(tau,n)] = R16[m][:] . W16[nn][:], K=256
//    R16 = [in(64) | x0h(64) | x0h(64) | x0l(64)], W16 = [Kmat | Ph | Pl | Ph]
// kP (ONE prep kernel, 192 blocks x 256 thr, ~93.7KB LDS -> 1 blk/CU, all
//     co-resident, ZERO cross-block deps -- avoids r13's spin-wait disaster and
//     r17's 1024-thr VGPR-64 spill):
//   blk 0..63   : chains P[tau]=A^(tau+1) via h/l MFMA (mm = 4 waves x 4 tiles)
//                 -> W16 Ph/Pl rows.
//   blk 64..191 : (1) one 64x128 input transpose tile -> R16[:,0:64);
//                 (2) self-sufficient Kv: Krylov first-8 from global-A rows in
//                     regs; ladder to H8; 8-col Krylov with H8 rows in regs;
//                 (3) Kmat (blk 64..127, tau=blk-64);
//                 (4) ladder to A64; r15 scan (4 q/block, ar+kvr in regs).
// kC: r15 verbatim (BK=32 dbuf, counted vmcnt(4), raw barriers, plain stores).

typedef _Float16 f16;
typedef __attribute__((ext_vector_type(8))) _Float16 f16x8;
typedef __attribute__((ext_vector_type(4))) float f32x4;

// ---------------- kP: chains | transpose+Kv+Kmat+scan ----------------
__global__ __launch_bounds__(256) void kP_prep(
    const float* __restrict__ A, const float* __restrict__ Bm,
    const float* __restrict__ inp,
    f16* __restrict__ W16, f16* __restrict__ R16)
{
  __shared__ __align__(16) char sA[93696];
  int t = threadIdx.x;
  int blk = blockIdx.x;
  int wave = t >> 6, lane = t & 63;
  int tn = wave;                           // 4 waves = 4 row strips of 16
  int kg = lane >> 4, fr = lane & 15;

  // D = P * Q^T (row-major h/l), h/l compensated; per-wave 4 col-tiles.
  auto mm = [&](f16 (*Ph)[72], f16 (*Pl)[72], f16 (*Qh)[72], f16 (*Ql)[72],
                f16 (*Dh)[72], f16 (*Dl)[72]) {
    f32x4 acc[4] = {};
    #pragma unroll
    for (int kk = 0; kk < 2; ++kk) {
      f16x8 ah = *(const f16x8*)&Ph[tn * 16 + fr][kk * 32 + kg * 8];
      f16x8 al = *(const f16x8*)&Pl[tn * 16 + fr][kk * 32 + kg * 8];
      #pragma unroll
      for (int tm = 0; tm < 4; ++tm) {
        f16x8 bh = *(const f16x8*)&Qh[tm * 16 + fr][kk * 32 + kg * 8];
        f16x8 bl = *(const f16x8*)&Ql[tm * 16 + fr][kk * 32 + kg * 8];
        acc[tm] = __builtin_amdgcn_mfma_f32_16x16x32_f16(ah, bh, acc[tm], 0, 0, 0);
        acc[tm] = __builtin_amdgcn_mfma_f32_16x16x32_f16(ah, bl, acc[tm], 0, 0, 0);
        acc[tm] = __builtin_amdgcn_mfma_f32_16x16x32_f16(al, bh, acc[tm], 0, 0, 0);
      }
    }
    #pragma unroll
    for (int tm = 0; tm < 4; ++tm)
      #pragma unroll
      for (int r = 0; r < 4; ++r) {
        float v = acc[tm][r];
        f16 h = (f16)v, l = (f16)(v - (float)h);
        Dh[tn * 16 + kg * 4 + r][tm * 16 + fr] = h;
        Dl[tn * 16 + kg * 4 + r][tm * 16 + fr] = l;
      }
    __syncthreads();
  };

  if (blk < 64) {
    // -------- chain blocks --------
    f16 (*Ah)[72]  = (f16 (*)[72])(sA + 0 * 9216);
    f16 (*Al)[72]  = (f16 (*)[72])(sA + 1 * 9216);
    f16 (*B0h)[72] = (f16 (*)[72])(sA + 2 * 9216);
    f16 (*B0l)[72] = (f16 (*)[72])(sA + 3 * 9216);
    f16 (*B1h)[72] = (f16 (*)[72])(sA + 4 * 9216);
    f16 (*B1l)[72] = (f16 (*)[72])(sA + 5 * 9216);
    f16 (*Y8h)[72] = (f16 (*)[72])(sA + 6 * 9216);
    f16 (*Y8l)[72] = (f16 (*)[72])(sA + 7 * 9216);
    f16 (*Ybh)[72] = (f16 (*)[72])(sA + 8 * 9216);
    f16 (*Ybl)[72] = (f16 (*)[72])(sA + 9 * 9216);

    int tau = blk;
    int e = tau + 1;
    int a = e >> 3, b = e & 7;

    auto cpy2 = [&](f16 (*Sh)[72], f16 (*Sl)[72], f16 (*Dh)[72], f16 (*Dl)[72]) {
      const unsigned* sh = (const unsigned*)Sh; unsigned* dh = (unsigned*)Dh;
      const unsigned* sl = (const unsigned*)Sl; unsigned* dl = (unsigned*)Dl;
      for (int idx = t; idx < 2304; idx += 256) { dh[idx] = sh[idx]; dl[idx] = sl[idx]; }
    };

    for (int idx = t; idx < 4096; idx += 256) {
      float v = A[idx];
      int r = idx >> 6, c2 = idx & 63;
      f16 h = (f16)v, l = (f16)(v - (float)h);
      Ah[r][c2] = h;  Al[r][c2] = l;
      B0h[c2][r] = h; B0l[c2][r] = l;
    }
    __syncthreads();

    f16 (*curH)[72] = B0h; f16 (*curL)[72] = B0l;
    f16 (*othH)[72] = B1h; f16 (*othL)[72] = B1l;
    auto swp = [&]() {
      f16 (*tH)[72] = curH; curH = othH; othH = tH;
      f16 (*tL)[72] = curL; curL = othL; othL = tL;
    };

    if (b == 1) cpy2(curH, curL, Ybh, Ybl);

    int loMax = (a >= 1) ? 8 : b;
    for (int i = 2; i <= loMax; ++i) {
      mm(curH, curL, Ah, Al, othH, othL);
      swp();
      if (i == b) cpy2(curH, curL, Ybh, Ybl);
      if (i == 8) cpy2(curH, curL, Y8h, Y8l);
    }

    f16 (*Rh)[72]; f16 (*Rl)[72]; bool tr;
    if (a == 0) {
      Rh = curH; Rl = curL; tr = true;              // result = Y_b^T
    } else {
      for (int idx = t; idx < 4096; idx += 256) {
        int i = idx >> 6, j = idx & 63;
        othH[i][j] = curH[j][i];
        othL[i][j] = curL[j][i];
      }
      swp();
      __syncthreads();
      for (int a2 = 2; a2 <= a; ++a2) {             // H_{a+1} = mm(H_a, Y8)
        mm(curH, curL, Y8h, Y8l, othH, othL);
        swp();
      }
      if (b >= 1) {                                 // P = mm(H_a, Y_b)
        mm(curH, curL, Ybh, Ybl, othH, othL);
        swp();
      }
      Rh = curH; Rl = curL; tr = false;
    }

    for (int idx = t; idx < 4096; idx += 256) {
      int wn = idx >> 6, m = idx & 63;
      f16 h = tr ? Rh[m][wn] : Rh[wn][m];
      f16 l = tr ? Rl[m][wn] : Rl[wn][m];
      f16* wrow = W16 + ((size_t)(tau * 64 + wn)) * 256;
      wrow[64 + m] = h; wrow[128 + m] = l; wrow[192 + m] = h;
    }
    return;
  }

  // -------- scan blocks (64..191) --------
  int bb = blk - 64;

  // (1) transpose: tile [64][133] f32 at offset 0 (dead after this phase)
  {
    float (*tile)[133] = (float (*)[133])sA;
    int j = bb >> 2, qb = (bb & 3) * 128;
    int k = t >> 2, sg = (t & 3) * 32;
    const float* src = inp + j * 32768 + k * 512 + qb + sg;
    #pragma unroll
    for (int i = 0; i < 32; i += 4)
      *(f32x4*)(&tile[k][sg + i]) = *(const f32x4*)(src + i);
    __syncthreads();
    #pragma unroll
    for (int rep = 0; rep < 4; ++rep) {
      int item = t + rep * 256;
      int qr = item >> 3, col8 = (item & 7) * 8;
      f16 tmp[8];
      #pragma unroll
      for (int kk = 0; kk < 8; ++kk)
        tmp[kk] = (f16)tile[col8 + kk][qr];
      *(f16x8*)(R16 + ((size_t)(j * 512 + qb + qr)) * 256 + col8) =
          *(const f16x8*)tmp;
    }
    __syncthreads();
  }

  f16 (*Ah)[72]  = (f16 (*)[72])(sA + 0);
  f16 (*Al)[72]  = (f16 (*)[72])(sA + 9216);
  f16 (*C0h)[72] = (f16 (*)[72])(sA + 18432);
  f16 (*C0l)[72] = (f16 (*)[72])(sA + 27648);
  f16 (*C1h)[72] = (f16 (*)[72])(sA + 36864);
  f16 (*C1l)[72] = (f16 (*)[72])(sA + 46080);
  f16 (*Sh)[72]  = (f16 (*)[72])(sA + 55296);
  f16 (*Sl)[72]  = (f16 (*)[72])(sA + 64512);
  float* KvF = (float*)(sA + 73728);       // [64][64] f32

  auto T = [&](f16 (*Sxh)[72], f16 (*Sxl)[72], f16 (*Dxh)[72], f16 (*Dxl)[72]) {
    for (int idx = t; idx < 4096; idx += 256) {
      int i2 = idx >> 6, j2 = idx & 63;
      Dxh[i2][j2] = Sxh[j2][i2];
      Dxl[i2][j2] = Sxl[j2][i2];
    }
    __syncthreads();
  };

  int L = lane;

  // (2a) init ladder + KvF[0]
  for (int idx = t; idx < 4096; idx += 256) {
    float v = A[idx];
    int r = idx >> 6, c2 = idx & 63;
    f16 h = (f16)v, l = (f16)(v - (float)h);
    Ah[r][c2] = h;  Al[r][c2] = l;
    C0h[c2][r] = h; C0l[c2][r] = l;
  }
  if (t < 64) KvF[t] = Bm[t];
  __syncthreads();

  // (2b) Krylov first 8 cols: KvF[j] = A * KvF[j-1] (A rows in regs, exact f32)
  {
    float ar1[64];
    const float* Arow = A + (size_t)L * 64;
    #pragma unroll
    for (int m = 0; m < 64; m += 4) {
      f32x4 v4 = *(const f32x4*)(Arow + m);
      ar1[m] = v4.x; ar1[m + 1] = v4.y; ar1[m + 2] = v4.z; ar1[m + 3] = v4.w;
    }
    for (int j = 1; j < 8; ++j) {
      float y = 0.f;
      #pragma unroll
      for (int m = 0; m < 64; m += 4) {
        f32x4 v = *(const f32x4*)(KvF + (j - 1) * 64 + m);
        y += ar1[m] * v.x + ar1[m + 1] * v.y + ar1[m + 2] * v.z + ar1[m + 3] * v.w;
      }
      if (t < 64) KvF[j * 64 + t] = y;
      __syncthreads();
    }
  }

  // (2c) ladder to H8: Y2,H2,Y4,H4,Y8,H8
  mm(C0h, C0l, Ah, Al, C1h, C1l);    // C1 = Y2
  T(C1h, C1l, C0h, C0l);             // C0 = H2
  mm(C1h, C1l, C0h, C0l, Sh, Sl);    // S  = Y4
  T(Sh, Sl, C1h, C1l);               // C1 = H4
  mm(Sh, Sl, C1h, C1l, C0h, C0l);    // C0 = Y8
  T(C0h, C0l, C1h, C1l);             // C1 = H8

  // (2d) Krylov 8-col blocks: KvF[8k+i] = A8 * KvF[8(k-1)+i], A8 rows = H8 rows
  {
    float ar8[64];
    #pragma unroll
    for (int mv = 0; mv < 64; mv += 8) {
      f16x8 hv = *(const f16x8*)&C1h[L][mv];
      f16x8 lv = *(const f16x8*)&C1l[L][mv];
      #pragma unroll
      for (int e2 = 0; e2 < 8; ++e2)
        ar8[mv + e2] = (float)hv[e2] + (float)lv[e2];
    }
    int i0 = wave * 2;
    for (int k = 1; k < 8; ++k) {
      float y0 = 0.f, y1 = 0.f;
      #pragma unroll
      for (int m = 0; m < 64; m += 4) {
        f32x4 u = *(const f32x4*)(KvF + (8 * (k - 1) + i0) * 64 + m);
        f32x4 w = *(const f32x4*)(KvF + (8 * (k - 1) + i0 + 1) * 64 + m);
        y0 += ar8[m] * u.x + ar8[m + 1] * u.y + ar8[m + 2] * u.z + ar8[m + 3] * u.w;
        y1 += ar8[m] * w.x + ar8[m + 1] * w.y + ar8[m + 2] * w.z + ar8[m + 3] * w.w;
      }
      KvF[(8 * k + i0) * 64 + L] = y0;
      KvF[(8 * k + i0 + 1) * 64 + L] = y1;
      __syncthreads();
    }
  }

  // (3) Kmat: blocks 64..127 handle tau = bb
  if (bb < 64) {
    int tau = bb;
    int wn = t >> 2, c4 = (t & 3) * 16;
    f16 tmp[16];
    #pragma unroll
    for (int ki = 0; ki < 16; ++ki) {
      int k = c4 + ki;
      tmp[ki] = (f16)((k <= tau) ? KvF[(tau - k) * 64 + wn] : 0.0f);
    }
    f16* wrow = W16 + ((size_t)(tau * 64 + wn)) * 256 + c4;
    *(f16x8*)(wrow)     = *(const f16x8*)(tmp);
    *(f16x8*)(wrow + 8) = *(const f16x8*)(tmp + 8);
  }

  // (4a) ladder continue to A64: A16, Y16, A32, Y32, A64
  mm(C1h, C1l, C0h, C0l, Sh, Sl);    // S  = A16 (H8 * Y8^T)
  T(Sh, Sl, C0h, C0l);               // C0 = Y16
  mm(Sh, Sl, C0h, C0l, C1h, C1l);    // C1 = A32
  T(C1h, C1l, C0h, C0l);             // C0 = Y32
  mm(C1h, C1l, C0h, C0l, Sh, Sl);    // S  = A64

  // (4b) scan: 4 waves, one q each (r15 body); xs/vs slabs in dead Ah region
  {
    int q = bb * 4 + wave;
    float* base = (float*)sA + wave * 144;
    float* xs = base;
    float* vs = base + 72;
    float ar[64], kvr[64];
    #pragma unroll
    for (int mv = 0; mv < 64; mv += 8) {
      f16x8 hv = *(const f16x8*)&Sh[L][mv];
      f16x8 lv = *(const f16x8*)&Sl[L][mv];
      #pragma unroll
      for (int e2 = 0; e2 < 8; ++e2)
        ar[mv + e2] = (float)hv[e2] + (float)lv[e2];
    }
    #pragma unroll
    for (int k = 0; k < 64; ++k) kvr[k] = KvF[(63 - k) * 64 + L];
    float x = 0.f;
    float v = inp[(size_t)L * 512 + q];
    for (int j = 0; j < 32; ++j) {
      float vn = (j < 31) ? inp[(size_t)((j + 1) * 64 + L) * 512 + q] : 0.f;
      f16 hh = (f16)x, ll = (f16)(x - (float)hh);
      f16* row = R16 + ((size_t)(j * 512 + q)) * 256;
      row[64 + L] = hh; row[128 + L] = hh; row[192 + L] = ll;
      xs[L] = x;
      vs[L] = v;
      float a0 = 0.f, a1 = 0.f, c0 = 0.f, c1 = 0.f;
      #pragma unroll
      for (int m = 0; m < 64; m += 4) {
        f32x4 xv = *(const f32x4*)(xs + m);   // same-addr broadcast
        f32x4 vv = *(const f32x4*)(vs + m);
        a0 += ar[m] * xv.x + ar[m + 1] * xv.y;
        a1 += ar[m + 2] * xv.z + ar[m + 3] * xv.w;
        c0 += kvr[m] * vv.x + kvr[m + 1] * vv.y;
        c1 += kvr[m + 2] * vv.z + kvr[m + 3] * vv.w;
      }
      x = (a0 + a1) + (c0 + c1);
      v = vn;
    }
  }
}

// ---------------- kC: C[16384 x 4096] = R16 @ W16^T (r15 verbatim) ----------------
#define STAGE32(ks, dbuf)                                                       \
  { _Pragma("unroll")                                                           \
    for (int it = 0; it < 2; ++it) {                                            \
      __builtin_amdgcn_global_load_lds(                                         \
        (const __attribute__((address_space(1))) void*)                         \
          (R16 + ((size_t)(mtb + w32 + it * 16 + l4)) * 256 + (ks) * 32 + swc32),\
        (__attribute__((address_space(3))) void*)((dbuf) + w * 1024 + it * 512),\
        16, 0, 0);                                                              \
      __builtin_amdgcn_global_load_lds(                                         \
        (const __attribute__((address_space(1))) void*)                         \
          (W16 + ((size_t)(ntb + w32 + it * 16 + l4)) * 256 + (ks) * 32 + swc32),\
        (__attribute__((address_space(3))) void*)((dbuf) + 4096 + w * 1024 + it * 512),\
        16, 0, 0);                                                              \
    } }

#define KSTEP32(sbuf)                                                           \
  { f16x8 af[4], bf[4];                                                         \
    _Pragma("unroll")                                                           \
    for (int i = 0; i < 4; ++i) {                                               \
      af[i] = *(const f16x8*)((sbuf) + (wr * 64 + i * 16 + fr) * 32 + scol);    \
      bf[i] = *(const f16x8*)((sbuf) + 4096 + (wc * 64 + i * 16 + fr) * 32 + scol);\
    }                                                                           \
    _Pragma("unroll")                                                           \
    for (int mi = 0; mi < 4; ++mi)                                              \
      _Pragma("unroll")                                                         \
      for (int ni = 0; ni < 4; ++ni)                                            \
        acc[mi][ni] = __builtin_amdgcn_mfma_f32_16x16x32_f16(                   \
            af[mi], bf[ni], acc[mi][ni], 0, 0, 0);                              \
  }

#define WAITN(n) asm volatile("s_waitcnt vmcnt(" #n ")" ::: "memory")
#define BAR()                                                                   \
  { __builtin_amdgcn_sched_barrier(0); __builtin_amdgcn_s_barrier();            \
    __builtin_amdgcn_sched_barrier(0); }

__global__ __launch_bounds__(256, 4) void kC_gemm(
    const f16* __restrict__ R16, const f16* __restrict__ W16,
    float* __restrict__ out)
{
  __shared__ __align__(16) char smem[34816];     // 2x16KB staging; epilogue alias
  f16* b0v = (f16*)smem;
  f16* b1v = b0v + 8192;
  float (*stg)[68] = (float (*)[68])smem;        // 34816B, aliased

  int wg = blockIdx.x;
  int swz = (wg & 7) * 512 + (wg >> 3);          // XCD-contiguous mt ranges
  int mt = swz >> 5, nt = swz & 31;
  int t = threadIdx.x, w = t >> 6, lane = t & 63;
  int wr = w >> 1, wc = w & 1;
  int kg = lane >> 4, fr = lane & 15;

  int l4 = lane >> 2;
  int swc32 = 8 * ((lane & 3) ^ ((lane >> 3) & 3));   // pre-swizzled src col (f16)
  int w32 = w * 32;
  int mtb = mt * 128, ntb = nt * 128;
  int scol = 8 * (kg ^ ((fr >> 1) & 3));              // swizzle-matched read col

  f32x4 acc[4][4] = {};

  STAGE32(0, b0v);
  STAGE32(1, b1v); WAITN(4); BAR(); KSTEP32(b0v); BAR();
  STAGE32(2, b0v); WAITN(4); BAR(); KSTEP32(b1v); BAR();
  STAGE32(3, b1v); WAITN(4); BAR(); KSTEP32(b0v); BAR();
  STAGE32(4, b0v); WAITN(4); BAR(); KSTEP32(b1v); BAR();
  STAGE32(5, b1v); WAITN(4); BAR(); KSTEP32(b0v); BAR();
  STAGE32(6, b0v); WAITN(4); BAR(); KSTEP32(b1v); BAR();
  STAGE32(7, b1v); WAITN(4); BAR(); KSTEP32(b0v); BAR();
  WAITN(0); BAR(); KSTEP32(b1v); BAR();

  int j = mt >> 2, q0 = (mt & 3) * 128;
  #pragma unroll
  for (int half = 0; half < 2; ++half) {
    if (wc == half) {
      #pragma unroll
      for (int mi = 0; mi < 4; ++mi)
        #pragma unroll
        for (int ni = 0; ni < 4; ++ni)
          #pragma unroll
          for (int r = 0; r < 4; ++r)
            stg[wr * 64 + mi * 16 + kg * 4 + r][ni * 16 + fr] = acc[mi][ni][r];
    }
    asm volatile("s_waitcnt lgkmcnt(0)" ::: "memory");
    BAR();
    int tau_g = nt * 2 + half;
    float* obase = out + (size_t)j * 2097152 + (size_t)tau_g * 32768 + (size_t)q0 * 64;
    #pragma unroll
    for (int it = 0; it < 8; ++it) {
      int fi = it * 1024 + t * 4;
      int rr = fi >> 6, cc = fi & 63;
      *(f32x4*)(obase + fi) = *(const f32x4*)(&stg[rr][cc]);
    }
    BAR();
  }
}

extern "C" void kernel_launch(void* const* d_in, const int* in_sizes, int n_in,
                              void* d_out, int out_size, void* d_ws, size_t ws_size,
                              hipStream_t stream)
{
  (void)in_sizes; (void)n_in; (void)out_size; (void)ws_size;
  const float* inp = (const float*)d_in[0];   // (2048, 8, 64) fp32
  const float* A   = (const float*)d_in[1];   // (64, 64) fp32
  const float* Bm  = (const float*)d_in[2];   // (64, 1) fp32
  float* out = (float*)d_out;                 // (2048, 8, 64, 64) fp32

  float* ws = (float*)d_ws;
  f16*  W16  = (f16*)(ws + 8192);             // 4096*256 f16 (2 MB)
  f16*  R16  = (f16*)((char*)d_ws + 2129920); // 16384*256 f16 (8 MB)

  hipLaunchKernelGGL(kP_prep, dim3(192),  dim3(256), 0, stream, A, Bm, inp, W16, R16);
  hipLaunchKernelGGL(kC_gemm, dim3(4096), dim3(256), 0, stream, R16, W16, out);
}

// Round 22
// 103.054 us; speedup vs baseline: 1.0464x; 1.0464x over previous
//
#include <hip/hip_runtime.h>

// MemoryProjection: x_t = A x_{t-1} + in_t * Bd, out = all states (2048,8,64,64) fp32.
// Chunked: out[j*64+tau] = A^(tau+1) x0_j + sum_{k<=tau} (A^(tau-k) Bd) in[j*64+k]
// => one fp16 MFMA GEMM: C[m=(j,q)][nn=(tau,n)] = R16[m][:] . W16[nn][:], K=256
//    R16 = [in(64) | x0h(64) | x0h(64) | x0l(64)], W16 = [Kmat | Ph | Pl | Ph]
// FINAL STRUCTURE (best = r15's 100.5us, rebalanced):
//   kA: 64 chain blocks ONLY (1024thr, h/l MFMA power chains -> W16 Ph/Pl, Kv, A64).
//   kB: 320 blocks x 256thr: 0..127 transpose (r21-verified 256thr port),
//       128..191 Kmat (coalesced), 192..319 conv+scan (r15 body, 4 q/block).
//   kC: r15 verbatim (BK=32 dbuf, counted vmcnt(4), raw barriers, plain stores).
// Session ledger: kC at HBM write floor (~42us; 6 null variants + r17 datum);
// prep ~58us is boundary/serial-latency bound (10 experiments: intra-prep opts
// null, fusions negative). This is the practical plateau of this decomposition.

typedef _Float16 f16;
typedef __attribute__((ext_vector_type(8))) _Float16 f16x8;
typedef __attribute__((ext_vector_type(4))) float f32x4;

// ---------------- kA: power chains via h/l MFMA ----------------
__global__ __launch_bounds__(1024) void kA_pow(
    const float* __restrict__ A, const float* __restrict__ Bm,
    float* __restrict__ A64, float* __restrict__ Kv,
    f16* __restrict__ W16)
{
  __shared__ __align__(16) char sA[92160];   // 10 x 9216B
  int t = threadIdx.x;

  f16 (*Ah)[72]  = (f16 (*)[72])(sA + 0 * 9216);
  f16 (*Al)[72]  = (f16 (*)[72])(sA + 1 * 9216);
  f16 (*B0h)[72] = (f16 (*)[72])(sA + 2 * 9216);
  f16 (*B0l)[72] = (f16 (*)[72])(sA + 3 * 9216);
  f16 (*B1h)[72] = (f16 (*)[72])(sA + 4 * 9216);
  f16 (*B1l)[72] = (f16 (*)[72])(sA + 5 * 9216);
  f16 (*Y8h)[72] = (f16 (*)[72])(sA + 6 * 9216);
  f16 (*Y8l)[72] = (f16 (*)[72])(sA + 7 * 9216);
  f16 (*Ybh)[72] = (f16 (*)[72])(sA + 8 * 9216);
  f16 (*Ybl)[72] = (f16 (*)[72])(sA + 9 * 9216);

  int tau = blockIdx.x;
  int e = tau + 1;
  int a = e >> 3, b = e & 7;
  int wave = t >> 6, lane = t & 63;
  int tn = wave >> 2, tm = wave & 3;       // 4x4 grid of 16x16 tiles
  int kg = lane >> 4, fr = lane & 15;

  auto mm = [&](f16 (*Ph)[72], f16 (*Pl)[72], f16 (*Qh)[72], f16 (*Ql)[72],
                f16 (*Dh)[72], f16 (*Dl)[72]) {
    f32x4 acc = {};
    #pragma unroll
    for (int kk = 0; kk < 2; ++kk) {
      f16x8 ah = *(const f16x8*)&Ph[tn * 16 + fr][kk * 32 + kg * 8];
      f16x8 al = *(const f16x8*)&Pl[tn * 16 + fr][kk * 32 + kg * 8];
      f16x8 bh = *(const f16x8*)&Qh[tm * 16 + fr][kk * 32 + kg * 8];
      f16x8 bl = *(const f16x8*)&Ql[tm * 16 + fr][kk * 32 + kg * 8];
      acc = __builtin_amdgcn_mfma_f32_16x16x32_f16(ah, bh, acc, 0, 0, 0);
      acc = __builtin_amdgcn_mfma_f32_16x16x32_f16(ah, bl, acc, 0, 0, 0);
      acc = __builtin_amdgcn_mfma_f32_16x16x32_f16(al, bh, acc, 0, 0, 0);
    }
    #pragma unroll
    for (int r = 0; r < 4; ++r) {
      float v = acc[r];
      f16 h = (f16)v, l = (f16)(v - (float)h);
      Dh[tn * 16 + kg * 4 + r][tm * 16 + fr] = h;
      Dl[tn * 16 + kg * 4 + r][tm * 16 + fr] = l;
    }
    __syncthreads();
  };
  auto cpy2 = [&](f16 (*Sh)[72], f16 (*Sl)[72], f16 (*Dh)[72], f16 (*Dl)[72]) {
    const unsigned* sh = (const unsigned*)Sh; unsigned* dh = (unsigned*)Dh;
    const unsigned* sl = (const unsigned*)Sl; unsigned* dl = (unsigned*)Dl;
    for (int idx = t; idx < 2304; idx += 1024) { dh[idx] = sh[idx]; dl[idx] = sl[idx]; }
  };

  for (int idx = t; idx < 4096; idx += 1024) {
    float v = A[idx];
    int r = idx >> 6, c2 = idx & 63;
    f16 h = (f16)v, l = (f16)(v - (float)h);
    Ah[r][c2] = h;  Al[r][c2] = l;
    B0h[c2][r] = h; B0l[c2][r] = l;
  }
  __syncthreads();

  f16 (*curH)[72] = B0h; f16 (*curL)[72] = B0l;
  f16 (*othH)[72] = B1h; f16 (*othL)[72] = B1l;
  auto swp = [&]() {
    f16 (*tH)[72] = curH; curH = othH; othH = tH;
    f16 (*tL)[72] = curL; curL = othL; othL = tL;
  };

  if (b == 1) cpy2(curH, curL, Ybh, Ybl);

  int loMax = (a >= 1) ? 8 : b;
  for (int i = 2; i <= loMax; ++i) {
    mm(curH, curL, Ah, Al, othH, othL);
    swp();
    if (i == b) cpy2(curH, curL, Ybh, Ybl);
    if (i == 8) cpy2(curH, curL, Y8h, Y8l);
  }

  f16 (*Rh)[72]; f16 (*Rl)[72]; bool tr;
  if (a == 0) {
    Rh = curH; Rl = curL; tr = true;                // result = Y_b^T
  } else {
    for (int idx = t; idx < 4096; idx += 1024) {
      int i = idx >> 6, j = idx & 63;
      othH[i][j] = curH[j][i];
      othL[i][j] = curL[j][i];
    }
    swp();
    __syncthreads();
    for (int a2 = 2; a2 <= a; ++a2) {               // H_{a+1} = mfma(H_a, Y8)
      mm(curH, curL, Y8h, Y8l, othH, othL);
      swp();
    }
    if (b >= 1) {                                   // P = mfma(H_a, Y_b)
      mm(curH, curL, Ybh, Ybl, othH, othL);
      swp();
    }
    Rh = curH; Rl = curL; tr = false;
  }

  for (int idx = t; idx < 4096; idx += 1024) {
    int wn = idx >> 6, m = idx & 63;
    f16 h = tr ? Rh[m][wn] : Rh[wn][m];
    f16 l = tr ? Rl[m][wn] : Rl[wn][m];
    f16* wrow = W16 + ((size_t)(tau * 64 + wn)) * 256;
    wrow[64 + m] = h; wrow[128 + m] = l; wrow[192 + m] = h;
    if (tau == 63) A64[idx] = (float)h + (float)l;
  }
  if (t < 64) {
    float s = 0.f;
    #pragma unroll 8
    for (int m = 0; m < 64; ++m) {
      float pv = tr ? ((float)Rh[m][t] + (float)Rl[m][t])
                    : ((float)Rh[t][m] + (float)Rl[t][m]);
      s += pv * Bm[m];
    }
    if (tau < 63) Kv[(tau + 1) * 64 + t] = s;
    else          Kv[t] = Bm[t];
  }
}

// ---------------- kB: transpose | Kmat | conv+scan (256 thr) ----------------
__global__ __launch_bounds__(256) void kB_prep(
    const float* __restrict__ inp, const float* __restrict__ Kv,
    const float* __restrict__ A64,
    f16* __restrict__ R16, f16* __restrict__ W16)
{
  __shared__ __align__(16) float sm[64 * 136];
  int t = threadIdx.x;
  int b = blockIdx.x;
  if (b < 128) {
    // transpose (r21-verified 256thr port): one (j,qb) 64x128 tile
    float (*tile)[133] = (float (*)[133])sm;
    int j = b >> 2, qb = (b & 3) * 128;
    int k = t >> 2, sg = (t & 3) * 32;
    const float* src = inp + j * 32768 + k * 512 + qb + sg;
    #pragma unroll
    for (int i = 0; i < 32; i += 4)
      *(f32x4*)(&tile[k][sg + i]) = *(const f32x4*)(src + i);
    __syncthreads();
    #pragma unroll
    for (int rep = 0; rep < 4; ++rep) {
      int item = t + rep * 256;
      int qr = item >> 3, col8 = (item & 7) * 8;
      f16 tmp[8];
      #pragma unroll
      for (int kk = 0; kk < 8; ++kk)
        tmp[kk] = (f16)tile[col8 + kk][qr];
      *(f16x8*)(R16 + ((size_t)(j * 512 + qb + qr)) * 256 + col8) =
          *(const f16x8*)tmp;
    }
  } else if (b < 192) {
    // Kmat rows (coalesced): 4 lanes per W16 row, 16 contiguous f16 each
    int tau = b - 128;
    for (int idx = t; idx < 4096; idx += 256) sm[idx] = Kv[idx];
    __syncthreads();
    int wn = t >> 2, c4 = (t & 3) * 16;
    f16 tmp[16];
    #pragma unroll
    for (int ki = 0; ki < 16; ++ki) {
      int k = c4 + ki;
      tmp[ki] = (f16)((k <= tau) ? sm[(tau - k) * 64 + wn] : 0.0f);
    }
    f16* wrow = W16 + ((size_t)(tau * 64 + wn)) * 256 + c4;
    *(f16x8*)(wrow)     = *(const f16x8*)(tmp);
    *(f16x8*)(wrow + 8) = *(const f16x8*)(tmp + 8);
  } else {
    // fused conv+scan (r15 body): 4 q per block, one wave each
    int wv = t >> 6, L = t & 63;
    int q = (b - 192) * 4 + wv;
    float* xs = sm + wv * 144;
    float* vs = xs + 72;
    float ar[64], kvr[64];
    #pragma unroll
    for (int m = 0; m < 64; m += 4) {
      f32x4 v4 = *(const f32x4*)(A64 + L * 64 + m);
      ar[m] = v4.x; ar[m + 1] = v4.y; ar[m + 2] = v4.z; ar[m + 3] = v4.w;
    }
    #pragma unroll
    for (int k = 0; k < 64; ++k) kvr[k] = Kv[(63 - k) * 64 + L];
    float x = 0.f;
    float v = inp[(size_t)L * 512 + q];
    for (int j = 0; j < 32; ++j) {
      float vn = (j < 31) ? inp[(size_t)((j + 1) * 64 + L) * 512 + q] : 0.f;
      f16 hh = (f16)x, ll = (f16)(x - (float)hh);
      f16* row = R16 + ((size_t)(j * 512 + q)) * 256;
      row[64 + L] = hh; row[128 + L] = hh; row[192 + L] = ll;
      xs[L] = x;
      vs[L] = v;
      float a0 = 0.f, a1 = 0.f, c0 = 0.f, c1 = 0.f;
      #pragma unroll
      for (int m = 0; m < 64; m += 4) {
        f32x4 xv = *(const f32x4*)(xs + m);   // same-addr broadcast, conflict-free
        f32x4 vv = *(const f32x4*)(vs + m);
        a0 += ar[m] * xv.x + ar[m + 1] * xv.y;
        a1 += ar[m + 2] * xv.z + ar[m + 3] * xv.w;
        c0 += kvr[m] * vv.x + kvr[m + 1] * vv.y;
        c1 += kvr[m + 2] * vv.z + kvr[m + 3] * vv.w;
      }
      x = (a0 + a1) + (c0 + c1);
      v = vn;
    }
  }
}

// ---------------- kC: C[16384 x 4096] = R16 @ W16^T (r15 verbatim) ----------------
#define STAGE32(ks, dbuf)                                                       \
  { _Pragma("unroll")                                                           \
    for (int it = 0; it < 2; ++it) {                                            \
      __builtin_amdgcn_global_load_lds(                                         \
        (const __attribute__((address_space(1))) void*)                         \
          (R16 + ((size_t)(mtb + w32 + it * 16 + l4)) * 256 + (ks) * 32 + swc32),\
        (__attribute__((address_space(3))) void*)((dbuf) + w * 1024 + it * 512),\
        16, 0, 0);                                                              \
      __builtin_amdgcn_global_load_lds(                                         \
        (const __attribute__((address_space(1))) void*)                         \
          (W16 + ((size_t)(ntb + w32 + it * 16 + l4)) * 256 + (ks) * 32 + swc32),\
        (__attribute__((address_space(3))) void*)((dbuf) + 4096 + w * 1024 + it * 512),\
        16, 0, 0);                                                              \
    } }

#define KSTEP32(sbuf)                                                           \
  { f16x8 af[4], bf[4];                                                         \
    _Pragma("unroll")                                                           \
    for (int i = 0; i < 4; ++i) {                                               \
      af[i] = *(const f16x8*)((sbuf) + (wr * 64 + i * 16 + fr) * 32 + scol);    \
      bf[i] = *(const f16x8*)((sbuf) + 4096 + (wc * 64 + i * 16 + fr) * 32 + scol);\
    }                                                                           \
    _Pragma("unroll")                                                           \
    for (int mi = 0; mi < 4; ++mi)                                              \
      _Pragma("unroll")                                                         \
      for (int ni = 0; ni < 4; ++ni)                                            \
        acc[mi][ni] = __builtin_amdgcn_mfma_f32_16x16x32_f16(                   \
            af[mi], bf[ni], acc[mi][ni], 0, 0, 0);                              \
  }

#define WAITN(n) asm volatile("s_waitcnt vmcnt(" #n ")" ::: "memory")
#define BAR()                                                                   \
  { __builtin_amdgcn_sched_barrier(0); __builtin_amdgcn_s_barrier();            \
    __builtin_amdgcn_sched_barrier(0); }

__global__ __launch_bounds__(256, 4) void kC_gemm(
    const f16* __restrict__ R16, const f16* __restrict__ W16,
    float* __restrict__ out)
{
  __shared__ __align__(16) char smem[34816];     // 2x16KB staging; epilogue alias
  f16* b0v = (f16*)smem;
  f16* b1v = b0v + 8192;
  float (*stg)[68] = (float (*)[68])smem;        // 34816B, aliased

  int wg = blockIdx.x;
  int swz = (wg & 7) * 512 + (wg >> 3);          // XCD-contiguous mt ranges
  int mt = swz >> 5, nt = swz & 31;
  int t = threadIdx.x, w = t >> 6, lane = t & 63;
  int wr = w >> 1, wc = w & 1;
  int kg = lane >> 4, fr = lane & 15;

  int l4 = lane >> 2;
  int swc32 = 8 * ((lane & 3) ^ ((lane >> 3) & 3));   // pre-swizzled src col (f16)
  int w32 = w * 32;
  int mtb = mt * 128, ntb = nt * 128;
  int scol = 8 * (kg ^ ((fr >> 1) & 3));              // swizzle-matched read col

  f32x4 acc[4][4] = {};

  STAGE32(0, b0v);
  STAGE32(1, b1v); WAITN(4); BAR(); KSTEP32(b0v); BAR();
  STAGE32(2, b0v); WAITN(4); BAR(); KSTEP32(b1v); BAR();
  STAGE32(3, b1v); WAITN(4); BAR(); KSTEP32(b0v); BAR();
  STAGE32(4, b0v); WAITN(4); BAR(); KSTEP32(b1v); BAR();
  STAGE32(5, b1v); WAITN(4); BAR(); KSTEP32(b0v); BAR();
  STAGE32(6, b0v); WAITN(4); BAR(); KSTEP32(b1v); BAR();
  STAGE32(7, b1v); WAITN(4); BAR(); KSTEP32(b0v); BAR();
  WAITN(0); BAR(); KSTEP32(b1v); BAR();

  int j = mt >> 2, q0 = (mt & 3) * 128;
  #pragma unroll
  for (int half = 0; half < 2; ++half) {
    if (wc == half) {
      #pragma unroll
      for (int mi = 0; mi < 4; ++mi)
        #pragma unroll
        for (int ni = 0; ni < 4; ++ni)
          #pragma unroll
          for (int r = 0; r < 4; ++r)
            stg[wr * 64 + mi * 16 + kg * 4 + r][ni * 16 + fr] = acc[mi][ni][r];
    }
    asm volatile("s_waitcnt lgkmcnt(0)" ::: "memory");
    BAR();
    int tau_g = nt * 2 + half;
    float* obase = out + (size_t)j * 2097152 + (size_t)tau_g * 32768 + (size_t)q0 * 64;
    #pragma unroll
    for (int it = 0; it < 8; ++it) {
      int fi = it * 1024 + t * 4;
      int rr = fi >> 6, cc = fi & 63;
      *(f32x4*)(obase + fi) = *(const f32x4*)(&stg[rr][cc]);
    }
    BAR();
  }
}

extern "C" void kernel_launch(void* const* d_in, const int* in_sizes, int n_in,
                              void* d_out, int out_size, void* d_ws, size_t ws_size,
                              hipStream_t stream)
{
  (void)in_sizes; (void)n_in; (void)out_size; (void)ws_size;
  const float* inp = (const float*)d_in[0];   // (2048, 8, 64) fp32
  const float* A   = (const float*)d_in[1];   // (64, 64) fp32
  const float* Bm  = (const float*)d_in[2];   // (64, 1) fp32
  float* out = (float*)d_out;                 // (2048, 8, 64, 64) fp32

  float* ws = (float*)d_ws;
  float* A64 = ws;                            // 4096 f32   (16 KB)
  float* Kv  = ws + 4096;                     // 4096 f32   (16 KB)
  f16*  W16  = (f16*)(ws + 8192);             // 4096*256 f16 (2 MB)
  f16*  R16  = (f16*)((char*)d_ws + 2129920); // 16384*256 f16 (8 MB)

  hipLaunchKernelGGL(kA_pow,  dim3(64),   dim3(1024), 0, stream, A, Bm, A64, Kv, W16);
  hipLaunchKernelGGL(kB_prep, dim3(320),  dim3(256),  0, stream, inp, Kv, A64, R16, W16);
  hipLaunchKernelGGL(kC_gemm, dim3(4096), dim3(256),  0, stream, R16, W16, out);
}